// Round 4
// baseline (957.622 us; speedup 1.0000x reference)
//
#include <hip/hip_runtime.h>
#include <hip/hip_bf16.h>

#define C 128

typedef __attribute__((ext_vector_type(8))) short bf16x8;
typedef __attribute__((ext_vector_type(4))) float f32x4;

__device__ __forceinline__ unsigned short f2bf(float f) {
    unsigned u = __builtin_bit_cast(unsigned, f);
    u += 0x7fff + ((u >> 16) & 1);          // RNE
    return (unsigned short)(u >> 16);
}
__device__ __forceinline__ float bflo(unsigned v) {
    return __builtin_bit_cast(float, v << 16);
}
__device__ __forceinline__ float bfhi(unsigned v) {
    return __builtin_bit_cast(float, v & 0xffff0000u);
}

// ---------------- k_emb: x_emb = x @ W1^T (bf16 out), mu = relu(x_emb) ------
__global__ __launch_bounds__(512) void k_emb(
    const float* __restrict__ x, const float* __restrict__ W1,
    unsigned short* __restrict__ x_emb, unsigned short* __restrict__ mu, int nN)
{
    __shared__ unsigned short Wl[C * C];   // bf16, XOR-swizzled 16B chunks
    const int t = threadIdx.x;
    for (int i = t; i < C * C / 8; i += 512) {
        int j = i >> 4, c = i & 15;
        const float* src = W1 + j * C + c * 8;
        float4 f0 = *(const float4*)src;
        float4 f1 = *(const float4*)(src + 4);
        alignas(16) unsigned short tmp[8] = {
            f2bf(f0.x), f2bf(f0.y), f2bf(f0.z), f2bf(f0.w),
            f2bf(f1.x), f2bf(f1.y), f2bf(f1.z), f2bf(f1.w)};
        int cs = c ^ (j & 7);
        *(uint4*)&Wl[j * C + cs * 8] = *(const uint4*)tmp;
    }
    __syncthreads();

    const int lane = t & 63, w = t >> 6;
    const int r0 = blockIdx.x * 128 + w * 16;
    if (r0 >= nN) return;
    const int lj = lane & 15, lk = lane >> 4;
    const int arow = r0 + lj;

    bf16x8 a[4];
    #pragma unroll
    for (int ks = 0; ks < 4; ++ks) {
        const float* ap = x + (size_t)arow * C + ks * 32 + lk * 8;
        float4 f0 = *(const float4*)ap;
        float4 f1 = *(const float4*)(ap + 4);
        alignas(16) unsigned short tmp[8] = {
            f2bf(f0.x), f2bf(f0.y), f2bf(f0.z), f2bf(f0.w),
            f2bf(f1.x), f2bf(f1.y), f2bf(f1.z), f2bf(f1.w)};
        a[ks] = *(const bf16x8*)tmp;
    }

    #pragma unroll
    for (int ct = 0; ct < 8; ++ct) {
        int j = ct * 16 + lj;
        f32x4 acc = {0.f, 0.f, 0.f, 0.f};
        #pragma unroll
        for (int ks = 0; ks < 4; ++ks) {
            int slot = (ks * 4 + lk) ^ (j & 7);
            bf16x8 b = *(const bf16x8*)&Wl[j * C + slot * 8];
            acc = __builtin_amdgcn_mfma_f32_16x16x32_bf16(a[ks], b, acc, 0, 0, 0);
        }
        #pragma unroll
        for (int r = 0; r < 4; ++r) {
            int row = r0 + lk * 4 + r;
            float v = acc[r];
            x_emb[(size_t)row * C + j] = f2bf(v);
            mu[(size_t)row * C + j]    = f2bf(fmaxf(v, 0.f));
        }
    }
}

// ---------------- k_mm2: t2 = mu @ W2^T, t3 = mu @ W3^T  (bf16 in/out) ------
__global__ __launch_bounds__(512) void k_mm2(
    const unsigned short* __restrict__ mu, const float* __restrict__ W2,
    const float* __restrict__ W3, unsigned short* __restrict__ t2,
    unsigned short* __restrict__ t3, int nN)
{
    __shared__ unsigned short Wl[2 * C * C];   // W2 then W3, swizzled
    const int t = threadIdx.x;
    for (int i = t; i < 2 * C * C / 8; i += 512) {
        int wsel = i >> 11, r = i & 2047;
        int j = r >> 4, c = r & 15;
        const float* src = (wsel ? W3 : W2) + j * C + c * 8;
        float4 f0 = *(const float4*)src;
        float4 f1 = *(const float4*)(src + 4);
        alignas(16) unsigned short tmp[8] = {
            f2bf(f0.x), f2bf(f0.y), f2bf(f0.z), f2bf(f0.w),
            f2bf(f1.x), f2bf(f1.y), f2bf(f1.z), f2bf(f1.w)};
        int cs = c ^ (j & 7);
        *(uint4*)&Wl[wsel * C * C + j * C + cs * 8] = *(const uint4*)tmp;
    }
    __syncthreads();

    const int lane = t & 63, w = t >> 6;
    const int r0 = blockIdx.x * 128 + w * 16;
    if (r0 >= nN) return;
    const int lj = lane & 15, lk = lane >> 4;
    const int arow = r0 + lj;

    bf16x8 a[4];
    #pragma unroll
    for (int ks = 0; ks < 4; ++ks)
        a[ks] = *(const bf16x8*)&mu[(size_t)arow * C + ks * 32 + lk * 8];

    #pragma unroll
    for (int ct = 0; ct < 8; ++ct) {
        int j = ct * 16 + lj;
        f32x4 acc2 = {0.f, 0.f, 0.f, 0.f};
        f32x4 acc3 = {0.f, 0.f, 0.f, 0.f};
        #pragma unroll
        for (int ks = 0; ks < 4; ++ks) {
            int slot = (ks * 4 + lk) ^ (j & 7);
            bf16x8 b2 = *(const bf16x8*)&Wl[j * C + slot * 8];
            bf16x8 b3 = *(const bf16x8*)&Wl[C * C + j * C + slot * 8];
            acc2 = __builtin_amdgcn_mfma_f32_16x16x32_bf16(a[ks], b2, acc2, 0, 0, 0);
            acc3 = __builtin_amdgcn_mfma_f32_16x16x32_bf16(a[ks], b3, acc3, 0, 0, 0);
        }
        #pragma unroll
        for (int r = 0; r < 4; ++r) {
            int row = r0 + lk * 4 + r;
            t2[(size_t)row * C + j] = f2bf(acc2[r]);
            t3[(size_t)row * C + j] = f2bf(acc3[r]);
        }
    }
}

// ---------------- degree count ----------------
__global__ void k_deg(const int* __restrict__ src, const int* __restrict__ dst,
                      int* __restrict__ deg, int nE, int nN)
{
    int e = blockIdx.x * 256 + threadIdx.x;
    if (e >= nE) return;
    atomicAdd(&deg[dst[e]], 1);
    atomicAdd(&deg[nN + src[e]], 1);
}

// ---------------- exclusive scan (3 kernels, chunk 512) ----------------
__global__ void k_scan1(const int* __restrict__ deg, int* __restrict__ off,
                        int* __restrict__ part, int n2)
{
    __shared__ int s[512];
    int t = threadIdx.x;
    int idx = blockIdx.x * 512 + t;
    int v = (idx < n2) ? deg[idx] : 0;
    s[t] = v;
    for (int o = 1; o < 512; o <<= 1) {
        __syncthreads();
        int x = (t >= o) ? s[t - o] : 0;
        __syncthreads();
        s[t] += x;
    }
    if (idx < n2) off[idx] = s[t] - v;
    if (t == 511) part[blockIdx.x] = s[511];
}

__global__ void k_scan2(int* __restrict__ part, int nb)
{
    __shared__ int s[512];
    int t = threadIdx.x;
    int v = (t < nb) ? part[t] : 0;
    s[t] = v;
    for (int o = 1; o < 512; o <<= 1) {
        __syncthreads();
        int x = (t >= o) ? s[t - o] : 0;
        __syncthreads();
        s[t] += x;
    }
    if (t < nb) part[t] = s[t] - v;
}

__global__ void k_scan3(int* __restrict__ off, const int* __restrict__ part, int n2)
{
    int idx = blockIdx.x * 256 + threadIdx.x;
    if (idx < n2) off[idx] += part[idx >> 9];
}

// ---------------- bucketed CSR fill -----------------------------------------
// Pass 1: append packed (key&127)<<17 | value into the bucket's contiguous
// CSR-span (bucket = 128 consecutive keys; base = off[b<<7]).
__global__ void k_part(const int* __restrict__ src, const int* __restrict__ dst,
                       const int* __restrict__ off, int* __restrict__ bcnt,
                       unsigned* __restrict__ tmp, int nE, int nN)
{
    int e = blockIdx.x * 256 + threadIdx.x;
    if (e >= nE) return;
    int s = src[e], d = dst[e];
    {   // in-list entry: key=d, value=s
        int key = d, b = key >> 7;
        int pos = off[b << 7] + atomicAdd(&bcnt[b], 1);
        tmp[pos] = ((unsigned)(key & 127) << 17) | (unsigned)s;
    }
    {   // out-list entry: key=nN+s, value=d
        int key = nN + s, b = key >> 7;
        int pos = off[b << 7] + atomicAdd(&bcnt[b], 1);
        tmp[pos] = ((unsigned)(key & 127) << 17) | (unsigned)d;
    }
}

// Pass 2: one block per bucket; re-scatter within the bucket's contiguous span.
__global__ __launch_bounds__(256) void k_place(
    const unsigned* __restrict__ tmp, const int* __restrict__ off,
    int* __restrict__ csr, int n2, int totE)
{
    __shared__ int lcnt[128];
    const int b = blockIdx.x;
    const int key0 = b << 7;
    const int keyend = min(key0 + 128, n2);
    const int s0 = off[key0];
    const int s1 = (keyend < n2) ? off[keyend] : totE;

    for (int i = threadIdx.x; i < 128; i += 256) lcnt[i] = 0;
    __syncthreads();

    for (int i = s0 + threadIdx.x; i < s1; i += 256) {
        unsigned p = tmp[i];
        int krel = p >> 17;
        int val  = p & 0x1FFFF;
        int pos  = off[key0 + krel] + atomicAdd(&lcnt[krel], 1);
        csr[pos] = val;
    }
}

// ---------------- aggregation (bf16 gathers, 8x predicated unroll) ----------
template<int FINAL>
__global__ __launch_bounds__(256) void k_agg(
    const unsigned short* __restrict__ t2, const unsigned short* __restrict__ t3,
    const unsigned short* __restrict__ x_emb, unsigned short* __restrict__ mu_out,
    float* __restrict__ out,
    const int* __restrict__ csr, const int* __restrict__ off,
    const int* __restrict__ deg, int nN)
{
    const int lane = threadIdx.x & 63, w = threadIdx.x >> 6;
    const int lo = lane * 2;
    float sx = 0.f, sy = 0.f;
    for (int g = blockIdx.x * 4 + w; g < nN; g += gridDim.x * 4) {
        unsigned base = *(const unsigned*)&x_emb[(size_t)g * C + lo];
        float ax = bflo(base), ay = bfhi(base);
        float bx = 0.f, by = 0.f;

        // in-neighbors -> t2 (predicated 8x unroll: all loads issue)
        {
            int o = off[g], e = o + deg[g];
            for (int i = o; i < e; i += 8) {
                #pragma unroll
                for (int j = 0; j < 8; ++j) {
                    int idx = i + j;
                    int u = csr[idx < e ? idx : e - 1];
                    unsigned v = *(const unsigned*)&t2[(size_t)u * C + lo];
                    unsigned vm = (idx < e) ? v : 0u;
                    if (j & 1) { bx += bflo(vm); by += bfhi(vm); }
                    else       { ax += bflo(vm); ay += bfhi(vm); }
                }
            }
        }
        // out-neighbors -> t3
        {
            int o = off[nN + g], e = o + deg[nN + g];
            for (int i = o; i < e; i += 8) {
                #pragma unroll
                for (int j = 0; j < 8; ++j) {
                    int idx = i + j;
                    int u = csr[idx < e ? idx : e - 1];
                    unsigned v = *(const unsigned*)&t3[(size_t)u * C + lo];
                    unsigned vm = (idx < e) ? v : 0u;
                    if (j & 1) { bx += bflo(vm); by += bfhi(vm); }
                    else       { ax += bflo(vm); ay += bfhi(vm); }
                }
            }
        }

        float rx = fmaxf(ax + bx, 0.f), ry = fmaxf(ay + by, 0.f);
        if (FINAL) {
            sx += rx; sy += ry;
        } else {
            unsigned pk = ((unsigned)f2bf(ry) << 16) | (unsigned)f2bf(rx);
            *(unsigned*)&mu_out[(size_t)g * C + lo] = pk;
        }
    }
    if (FINAL) {
        __shared__ float red[512];
        red[threadIdx.x * 2]     = sx;
        red[threadIdx.x * 2 + 1] = sy;
        __syncthreads();
        if (w == 0) {
            float ax = red[lane * 2]         + red[(64 + lane) * 2] +
                       red[(128 + lane) * 2] + red[(192 + lane) * 2];
            float ay = red[lane * 2 + 1]         + red[(64 + lane) * 2 + 1] +
                       red[(128 + lane) * 2 + 1] + red[(192 + lane) * 2 + 1];
            atomicAdd(&out[lane * 2], ax);
            atomicAdd(&out[lane * 2 + 1], ay);
        }
    }
}

extern "C" void kernel_launch(void* const* d_in, const int* in_sizes, int n_in,
                              void* d_out, int out_size, void* d_ws, size_t ws_size,
                              hipStream_t stream)
{
    const float* x  = (const float*)d_in[0];
    const int*   ei = (const int*)d_in[1];
    const float* W1 = (const float*)d_in[2];
    const float* W2 = (const float*)d_in[3];
    const float* W3 = (const float*)d_in[4];
    float* out = (float*)d_out;

    const int nN = in_sizes[0] / C;
    const int nE = in_sizes[1] / 2;
    const int* src = ei;
    const int* dst = ei + nE;

    const size_t SZH = (size_t)nN * C * 2;   // bf16 node array
    char* p = (char*)d_ws;
    auto alloc = [&](size_t bytes) {
        char* r = p;
        p += (bytes + 511) & ~(size_t)511;
        return r;
    };
    unsigned short* x_emb = (unsigned short*)alloc(SZH);
    unsigned short* mu    = (unsigned short*)alloc(SZH);
    unsigned short* t2    = (unsigned short*)alloc(SZH);
    unsigned short* t3    = (unsigned short*)alloc(SZH);
    int* deg  = (int*)alloc((size_t)2 * nN * 4);
    int* off  = (int*)alloc((size_t)2 * nN * 4);
    int* part = (int*)alloc(512 * 4);
    int* bcnt = (int*)alloc(4096 * 4);
    unsigned* tmp = (unsigned*)alloc((size_t)2 * nE * 4);
    int* csr  = (int*)alloc((size_t)2 * nE * 4);

    const int n2 = 2 * nN;
    const int nbuck = (n2 + 127) >> 7;

    hipMemsetAsync(deg, 0, (size_t)n2 * 4, stream);
    hipMemsetAsync(bcnt, 0, (size_t)nbuck * 4, stream);
    hipMemsetAsync(out, 0, (size_t)out_size * 4, stream);

    const int mm_grid = (nN + 127) / 128;

    // iteration 1: mu = relu(x @ W1^T)
    k_emb<<<mm_grid, 512, 0, stream>>>(x, W1, x_emb, mu, nN);

    // CSR build
    k_deg<<<(nE + 255) / 256, 256, 0, stream>>>(src, dst, deg, nE, nN);
    const int nb = (n2 + 511) / 512;
    k_scan1<<<nb, 512, 0, stream>>>(deg, off, part, n2);
    k_scan2<<<1, 512, 0, stream>>>(part, nb);
    k_scan3<<<(n2 + 255) / 256, 256, 0, stream>>>(off, part, n2);
    k_part<<<(nE + 255) / 256, 256, 0, stream>>>(src, dst, off, bcnt, tmp, nE, nN);
    k_place<<<nbuck, 256, 0, stream>>>(tmp, off, csr, n2, 2 * nE);

    // iteration 2
    k_mm2<<<mm_grid, 512, 0, stream>>>(mu, W2, W3, t2, t3, nN);
    k_agg<0><<<(nN + 3) / 4, 256, 0, stream>>>(t2, t3, x_emb, mu, out, csr, off, deg, nN);
    // iteration 3 (fused final reduce; mu never materialized)
    k_mm2<<<mm_grid, 512, 0, stream>>>(mu, W2, W3, t2, t3, nN);
    k_agg<1><<<2048, 256, 0, stream>>>(t2, t3, x_emb, nullptr, out, csr, off, deg, nN);
}

// Round 5
// 580.936 us; speedup vs baseline: 1.6484x; 1.6484x over previous
//
#include <hip/hip_runtime.h>
#include <hip/hip_bf16.h>

#define C 128
#define NBMAX 256      // max coarse buckets (key >> 10)
#define EPB 16384      // entries per k_part2 block (8192 edges)

typedef __attribute__((ext_vector_type(8))) short bf16x8;
typedef __attribute__((ext_vector_type(4))) float f32x4;

__device__ __forceinline__ unsigned short f2bf(float f) {
    unsigned u = __builtin_bit_cast(unsigned, f);
    u += 0x7fff + ((u >> 16) & 1);          // RNE
    return (unsigned short)(u >> 16);
}
__device__ __forceinline__ float bflo(unsigned v) {
    return __builtin_bit_cast(float, v << 16);
}
__device__ __forceinline__ float bfhi(unsigned v) {
    return __builtin_bit_cast(float, v & 0xffff0000u);
}

// ---------------- k_emb: x_emb = x @ W1^T (bf16 out), mu = relu(x_emb) ------
__global__ __launch_bounds__(512) void k_emb(
    const float* __restrict__ x, const float* __restrict__ W1,
    unsigned short* __restrict__ x_emb, unsigned short* __restrict__ mu, int nN)
{
    __shared__ unsigned short Wl[C * C];   // bf16, XOR-swizzled 16B chunks
    const int t = threadIdx.x;
    for (int i = t; i < C * C / 8; i += 512) {
        int j = i >> 4, c = i & 15;
        const float* src = W1 + j * C + c * 8;
        float4 f0 = *(const float4*)src;
        float4 f1 = *(const float4*)(src + 4);
        alignas(16) unsigned short tmp[8] = {
            f2bf(f0.x), f2bf(f0.y), f2bf(f0.z), f2bf(f0.w),
            f2bf(f1.x), f2bf(f1.y), f2bf(f1.z), f2bf(f1.w)};
        int cs = c ^ (j & 7);
        *(uint4*)&Wl[j * C + cs * 8] = *(const uint4*)tmp;
    }
    __syncthreads();

    const int lane = t & 63, w = t >> 6;
    const int r0 = blockIdx.x * 128 + w * 16;
    if (r0 >= nN) return;
    const int lj = lane & 15, lk = lane >> 4;
    const int arow = r0 + lj;

    bf16x8 a[4];
    #pragma unroll
    for (int ks = 0; ks < 4; ++ks) {
        const float* ap = x + (size_t)arow * C + ks * 32 + lk * 8;
        float4 f0 = *(const float4*)ap;
        float4 f1 = *(const float4*)(ap + 4);
        alignas(16) unsigned short tmp[8] = {
            f2bf(f0.x), f2bf(f0.y), f2bf(f0.z), f2bf(f0.w),
            f2bf(f1.x), f2bf(f1.y), f2bf(f1.z), f2bf(f1.w)};
        a[ks] = *(const bf16x8*)tmp;
    }

    #pragma unroll
    for (int ct = 0; ct < 8; ++ct) {
        int j = ct * 16 + lj;
        f32x4 acc = {0.f, 0.f, 0.f, 0.f};
        #pragma unroll
        for (int ks = 0; ks < 4; ++ks) {
            int slot = (ks * 4 + lk) ^ (j & 7);
            bf16x8 b = *(const bf16x8*)&Wl[j * C + slot * 8];
            acc = __builtin_amdgcn_mfma_f32_16x16x32_bf16(a[ks], b, acc, 0, 0, 0);
        }
        #pragma unroll
        for (int r = 0; r < 4; ++r) {
            int row = r0 + lk * 4 + r;
            float v = acc[r];
            x_emb[(size_t)row * C + j] = f2bf(v);
            mu[(size_t)row * C + j]    = f2bf(fmaxf(v, 0.f));
        }
    }
}

// ---------------- k_mm2: t2 = mu @ W2^T, t3 = mu @ W3^T  (bf16 in/out) ------
__global__ __launch_bounds__(512) void k_mm2(
    const unsigned short* __restrict__ mu, const float* __restrict__ W2,
    const float* __restrict__ W3, unsigned short* __restrict__ t2,
    unsigned short* __restrict__ t3, int nN)
{
    __shared__ unsigned short Wl[2 * C * C];   // W2 then W3, swizzled
    const int t = threadIdx.x;
    for (int i = t; i < 2 * C * C / 8; i += 512) {
        int wsel = i >> 11, r = i & 2047;
        int j = r >> 4, c = r & 15;
        const float* src = (wsel ? W3 : W2) + j * C + c * 8;
        float4 f0 = *(const float4*)src;
        float4 f1 = *(const float4*)(src + 4);
        alignas(16) unsigned short tmp[8] = {
            f2bf(f0.x), f2bf(f0.y), f2bf(f0.z), f2bf(f0.w),
            f2bf(f1.x), f2bf(f1.y), f2bf(f1.z), f2bf(f1.w)};
        int cs = c ^ (j & 7);
        *(uint4*)&Wl[wsel * C * C + j * C + cs * 8] = *(const uint4*)tmp;
    }
    __syncthreads();

    const int lane = t & 63, w = t >> 6;
    const int r0 = blockIdx.x * 128 + w * 16;
    if (r0 >= nN) return;
    const int lj = lane & 15, lk = lane >> 4;
    const int arow = r0 + lj;

    bf16x8 a[4];
    #pragma unroll
    for (int ks = 0; ks < 4; ++ks)
        a[ks] = *(const bf16x8*)&mu[(size_t)arow * C + ks * 32 + lk * 8];

    #pragma unroll
    for (int ct = 0; ct < 8; ++ct) {
        int j = ct * 16 + lj;
        f32x4 acc2 = {0.f, 0.f, 0.f, 0.f};
        f32x4 acc3 = {0.f, 0.f, 0.f, 0.f};
        #pragma unroll
        for (int ks = 0; ks < 4; ++ks) {
            int slot = (ks * 4 + lk) ^ (j & 7);
            bf16x8 b2 = *(const bf16x8*)&Wl[j * C + slot * 8];
            bf16x8 b3 = *(const bf16x8*)&Wl[C * C + j * C + slot * 8];
            acc2 = __builtin_amdgcn_mfma_f32_16x16x32_bf16(a[ks], b2, acc2, 0, 0, 0);
            acc3 = __builtin_amdgcn_mfma_f32_16x16x32_bf16(a[ks], b3, acc3, 0, 0, 0);
        }
        #pragma unroll
        for (int r = 0; r < 4; ++r) {
            int row = r0 + lk * 4 + r;
            t2[(size_t)row * C + j] = f2bf(acc2[r]);
            t3[(size_t)row * C + j] = f2bf(acc3[r]);
        }
    }
}

// ---------------- degree count ----------------
__global__ void k_deg(const int* __restrict__ src, const int* __restrict__ dst,
                      int* __restrict__ deg, int nE, int nN)
{
    int e = blockIdx.x * 256 + threadIdx.x;
    if (e >= nE) return;
    atomicAdd(&deg[dst[e]], 1);
    atomicAdd(&deg[nN + src[e]], 1);
}

// ---------------- exclusive scan (3 kernels, chunk 512) ----------------
__global__ void k_scan1(const int* __restrict__ deg, int* __restrict__ off,
                        int* __restrict__ part, int n2)
{
    __shared__ int s[512];
    int t = threadIdx.x;
    int idx = blockIdx.x * 512 + t;
    int v = (idx < n2) ? deg[idx] : 0;
    s[t] = v;
    for (int o = 1; o < 512; o <<= 1) {
        __syncthreads();
        int x = (t >= o) ? s[t - o] : 0;
        __syncthreads();
        s[t] += x;
    }
    if (idx < n2) off[idx] = s[t] - v;
    if (t == 511) part[blockIdx.x] = s[511];
}

__global__ void k_scan2(int* __restrict__ part, int nb)
{
    __shared__ int s[512];
    int t = threadIdx.x;
    int v = (t < nb) ? part[t] : 0;
    s[t] = v;
    for (int o = 1; o < 512; o <<= 1) {
        __syncthreads();
        int x = (t >= o) ? s[t - o] : 0;
        __syncthreads();
        s[t] += x;
    }
    if (t < nb) part[t] = s[t] - v;
}

__global__ void k_scan3(int* __restrict__ off, const int* __restrict__ part, int n2)
{
    int idx = blockIdx.x * 256 + threadIdx.x;
    if (idx < n2) off[idx] += part[idx >> 9];
}

// ---------------- CSR build pass 1: block-local counting sort ---------------
// Coarse bucket = key >> 10. Each block LDS-sorts EPB entries by bucket, then
// appends each bucket's run to tmp with ONE global atomic per block per bucket
// (counters padded to separate cache lines).
__global__ __launch_bounds__(512) void k_part2(
    const int* __restrict__ src, const int* __restrict__ dst,
    const int* __restrict__ off, int* __restrict__ bcnt,
    unsigned* __restrict__ tmp, int nE, int nN, int n2)
{
    __shared__ unsigned sbuf[EPB];
    __shared__ unsigned char bid[EPB];
    __shared__ int hist[NBMAX], lstart[NBMAX], cur[NBMAX], gbase[NBMAX];

    const int t = threadIdx.x;
    const int e0 = blockIdx.x * (EPB / 2);
    const int e1 = min(e0 + EPB / 2, nE);

    for (int b = t; b < NBMAX; b += 512) { hist[b] = 0; cur[b] = 0; }
    __syncthreads();

    // pass A: histogram over coarse buckets
    for (int e = e0 + t; e < e1; e += 512) {
        int s = src[e], d = dst[e];
        atomicAdd(&hist[d >> 10], 1);
        atomicAdd(&hist[(nN + s) >> 10], 1);
    }
    __syncthreads();

    // inclusive scan over NBMAX in LDS (all threads hit barriers)
    for (int o = 1; o < NBMAX; o <<= 1) {
        int v = 0;
        if (t < NBMAX && t >= o) v = hist[t - o];
        __syncthreads();
        if (t < NBMAX) hist[t] += v;
        __syncthreads();
    }
    if (t < NBMAX) {
        int ls = (t == 0) ? 0 : hist[t - 1];
        lstart[t] = ls;
        int c = hist[t] - ls;
        if (c > 0)
            gbase[t] = off[t << 10] + atomicAdd(&bcnt[t * 16], c);
    }
    __syncthreads();

    // pass B: place entries into LDS-sorted buffer
    for (int e = e0 + t; e < e1; e += 512) {
        int s = src[e], d = dst[e];
        {
            int key = d, b = key >> 10, krel = key & 1023;
            int pos = lstart[b] + atomicAdd(&cur[b], 1);
            sbuf[pos] = ((unsigned)krel << 17) | (unsigned)s;
            bid[pos] = (unsigned char)b;
        }
        {
            int key = nN + s, b = key >> 10, krel = key & 1023;
            int pos = lstart[b] + atomicAdd(&cur[b], 1);
            sbuf[pos] = ((unsigned)krel << 17) | (unsigned)d;
            bid[pos] = (unsigned char)b;
        }
    }
    __syncthreads();

    // write runs contiguously to tmp
    const int nent = 2 * (e1 - e0);
    for (int j = t; j < nent; j += 512) {
        int b = bid[j];
        tmp[gbase[b] + (j - lstart[b])] = sbuf[j];
    }
}

// ---------------- CSR build pass 2: per-bucket scatter ----------------------
__global__ __launch_bounds__(256) void k_place(
    const unsigned* __restrict__ tmp, const int* __restrict__ off,
    int* __restrict__ csr, int n2, int totE)
{
    __shared__ int lcnt[1024];
    const int key0 = blockIdx.x << 10;
    const int keyend = min(key0 + 1024, n2);
    const int s0 = off[key0];
    const int s1 = (keyend < n2) ? off[keyend] : totE;

    for (int i = threadIdx.x; i < 1024; i += 256) lcnt[i] = 0;
    __syncthreads();

    for (int i = s0 + threadIdx.x; i < s1; i += 256) {
        unsigned p = tmp[i];
        int krel = p >> 17;
        int val  = p & 0x1FFFF;
        int pos  = off[key0 + krel] + atomicAdd(&lcnt[krel], 1);
        csr[pos] = val;
    }
}

// ---------------- aggregation (bf16 gathers, 8x predicated unroll) ----------
template<int FINAL>
__global__ __launch_bounds__(256) void k_agg(
    const unsigned short* __restrict__ t2, const unsigned short* __restrict__ t3,
    const unsigned short* __restrict__ x_emb, unsigned short* __restrict__ mu_out,
    float* __restrict__ out,
    const int* __restrict__ csr, const int* __restrict__ off,
    const int* __restrict__ deg, int nN)
{
    const int lane = threadIdx.x & 63, w = threadIdx.x >> 6;
    const int lo = lane * 2;
    float sx = 0.f, sy = 0.f;
    for (int g = blockIdx.x * 4 + w; g < nN; g += gridDim.x * 4) {
        unsigned base = *(const unsigned*)&x_emb[(size_t)g * C + lo];
        float ax = bflo(base), ay = bfhi(base);
        float bx = 0.f, by = 0.f;

        {
            int o = off[g], e = o + deg[g];
            for (int i = o; i < e; i += 8) {
                #pragma unroll
                for (int j = 0; j < 8; ++j) {
                    int idx = i + j;
                    int u = csr[idx < e ? idx : e - 1];
                    unsigned v = *(const unsigned*)&t2[(size_t)u * C + lo];
                    unsigned vm = (idx < e) ? v : 0u;
                    if (j & 1) { bx += bflo(vm); by += bfhi(vm); }
                    else       { ax += bflo(vm); ay += bfhi(vm); }
                }
            }
        }
        {
            int o = off[nN + g], e = o + deg[nN + g];
            for (int i = o; i < e; i += 8) {
                #pragma unroll
                for (int j = 0; j < 8; ++j) {
                    int idx = i + j;
                    int u = csr[idx < e ? idx : e - 1];
                    unsigned v = *(const unsigned*)&t3[(size_t)u * C + lo];
                    unsigned vm = (idx < e) ? v : 0u;
                    if (j & 1) { bx += bflo(vm); by += bfhi(vm); }
                    else       { ax += bflo(vm); ay += bfhi(vm); }
                }
            }
        }

        float rx = fmaxf(ax + bx, 0.f), ry = fmaxf(ay + by, 0.f);
        if (FINAL) {
            sx += rx; sy += ry;
        } else {
            unsigned pk = ((unsigned)f2bf(ry) << 16) | (unsigned)f2bf(rx);
            *(unsigned*)&mu_out[(size_t)g * C + lo] = pk;
        }
    }
    if (FINAL) {
        __shared__ float red[512];
        red[threadIdx.x * 2]     = sx;
        red[threadIdx.x * 2 + 1] = sy;
        __syncthreads();
        if (w == 0) {
            float ax = red[lane * 2]         + red[(64 + lane) * 2] +
                       red[(128 + lane) * 2] + red[(192 + lane) * 2];
            float ay = red[lane * 2 + 1]         + red[(64 + lane) * 2 + 1] +
                       red[(128 + lane) * 2 + 1] + red[(192 + lane) * 2 + 1];
            atomicAdd(&out[lane * 2], ax);
            atomicAdd(&out[lane * 2 + 1], ay);
        }
    }
}

extern "C" void kernel_launch(void* const* d_in, const int* in_sizes, int n_in,
                              void* d_out, int out_size, void* d_ws, size_t ws_size,
                              hipStream_t stream)
{
    const float* x  = (const float*)d_in[0];
    const int*   ei = (const int*)d_in[1];
    const float* W1 = (const float*)d_in[2];
    const float* W2 = (const float*)d_in[3];
    const float* W3 = (const float*)d_in[4];
    float* out = (float*)d_out;

    const int nN = in_sizes[0] / C;
    const int nE = in_sizes[1] / 2;
    const int* src = ei;
    const int* dst = ei + nE;

    const size_t SZH = (size_t)nN * C * 2;   // bf16 node array
    char* p = (char*)d_ws;
    auto alloc = [&](size_t bytes) {
        char* r = p;
        p += (bytes + 511) & ~(size_t)511;
        return r;
    };
    unsigned short* x_emb = (unsigned short*)alloc(SZH);
    unsigned short* mu    = (unsigned short*)alloc(SZH);
    unsigned short* t2    = (unsigned short*)alloc(SZH);
    unsigned short* t3    = (unsigned short*)alloc(SZH);
    int* deg  = (int*)alloc((size_t)2 * nN * 4);
    int* off  = (int*)alloc((size_t)2 * nN * 4);
    int* part = (int*)alloc(512 * 4);
    int* bcnt = (int*)alloc((size_t)NBMAX * 16 * 4);
    unsigned* tmp = (unsigned*)alloc((size_t)2 * nE * 4);
    int* csr  = (int*)alloc((size_t)2 * nE * 4);

    const int n2 = 2 * nN;
    const int nbuck = (n2 + 1023) >> 10;     // coarse buckets (<= NBMAX)

    hipMemsetAsync(deg, 0, (size_t)n2 * 4, stream);
    hipMemsetAsync(bcnt, 0, (size_t)NBMAX * 16 * 4, stream);
    hipMemsetAsync(out, 0, (size_t)out_size * 4, stream);

    const int mm_grid = (nN + 127) / 128;

    // iteration 1: mu = relu(x @ W1^T)
    k_emb<<<mm_grid, 512, 0, stream>>>(x, W1, x_emb, mu, nN);

    // CSR build
    k_deg<<<(nE + 255) / 256, 256, 0, stream>>>(src, dst, deg, nE, nN);
    const int nb = (n2 + 511) / 512;
    k_scan1<<<nb, 512, 0, stream>>>(deg, off, part, n2);
    k_scan2<<<1, 512, 0, stream>>>(part, nb);
    k_scan3<<<(n2 + 255) / 256, 256, 0, stream>>>(off, part, n2);
    const int npart = (nE + EPB / 2 - 1) / (EPB / 2);
    k_part2<<<npart, 512, 0, stream>>>(src, dst, off, bcnt, tmp, nE, nN, n2);
    k_place<<<nbuck, 256, 0, stream>>>(tmp, off, csr, n2, 2 * nE);

    // iteration 2
    k_mm2<<<mm_grid, 512, 0, stream>>>(mu, W2, W3, t2, t3, nN);
    k_agg<0><<<(nN + 3) / 4, 256, 0, stream>>>(t2, t3, x_emb, mu, out, csr, off, deg, nN);
    // iteration 3 (fused final reduce; mu never materialized)
    k_mm2<<<mm_grid, 512, 0, stream>>>(mu, W2, W3, t2, t3, nN);
    k_agg<1><<<2048, 256, 0, stream>>>(t2, t3, x_emb, nullptr, out, csr, off, deg, nN);
}